// Round 1
// baseline (113.604 us; speedup 1.0000x reference)
//
#include <hip/hip_runtime.h>
#include <hip/hip_bf16.h>

// ---------------------------------------------------------------------------
// preds[i][c] = sum_j exp(cos(e_i, t_j)) [y_j==c]  /  sum_j exp(cos(e_i, t_j))
// where e = normalize(mlp(X)), t = normalize(mlp(x_train)).
// exp needs no max-subtraction: cosine <= 1 so exp(s) <= e.
//
// Pipeline (all on `stream`):
//   memset acc=0
//   k_prep  : W1,W2 -> bf16 MFMA B-frag layout; y -> V[16384x16] frag layout
//             (V = onehot(y) cols 0..9, ones col 10, zero 11..15)
//   k_embed : MFMA MLP (64-row tiles, per-wave 16-row strips, H via private
//             LDS), row-normalize, store bf16 embeddings in frag-ready layout
//   k_main  : flash-style sweep. block = 64 test rows, 4 waves split train.
//             S = A@B (two 16x16x32 bf16 MFMAs / 16 trains), exp, bf16,
//             LDS transpose (per-wave private, no barrier), O += P@V MFMA.
//             LDS wave-combine then atomicAdd into acc[8192][16].
//   k_final : preds = acc[:,0:10] / acc[:,10]
//
// Frag-ready layout for a bf16 matrix M[row][k] (16-row tiles, K=64):
//   elem(row,k) at tile(row>>4), kt(k>>5): ((row>>4)*2+kt)*512
//                + ( ((k>>3)&3)*16 + (row&15) )*8 + (k&7)
//   so a frag load is *(short8*)(base + (tile*2+kt)*512 + lane*8): one dwordx4.
// ---------------------------------------------------------------------------

typedef __attribute__((ext_vector_type(8))) short short8;    // 8 bf16 = 4 VGPR
typedef __attribute__((ext_vector_type(4))) float floatx4;
typedef unsigned short u16;

__device__ __forceinline__ u16 f2bf(float f) {  // RNE float->bf16
    unsigned u = __float_as_uint(f);
    u += 0x7fffu + ((u >> 16) & 1u);
    return (u16)(u >> 16);
}

// ------------------------------- prep --------------------------------------
__global__ __launch_bounds__(256) void k_prep(
    const float* __restrict__ W1, const float* __restrict__ W2,
    const int* __restrict__ y, u16* __restrict__ W1f,
    u16* __restrict__ W2f, u16* __restrict__ Vf)
{
    int tid = blockIdx.x * 256 + threadIdx.x;
    if (tid < 8192) {
        // W1 [64][128] -> B-frags: fid = (n>>4)*2 + (k>>5)
        int k = tid >> 7, n = tid & 127;
        int fid = (n >> 4) * 2 + (k >> 5);
        int l   = ((k >> 3) & 3) * 16 + (n & 15);
        W1f[fid * 512 + l * 8 + (k & 7)] = f2bf(W1[k * 128 + n]);
        // W2 [128][64] -> B-frags: fid = (n>>4)*4 + (k>>5)
        int k2 = tid >> 6, n2 = tid & 63;
        int fid2 = (n2 >> 4) * 4 + (k2 >> 5);
        int l2   = ((k2 >> 3) & 3) * 16 + (n2 & 15);
        W2f[fid2 * 512 + l2 * 8 + (k2 & 7)] = f2bf(W2[k2 * 64 + n2]);
    }
    if (tid < 262144) {
        // V [16384][16]: onehot + ones col 10. B-frag over k=train, n=class.
        int j = tid >> 4, c = tid & 15;
        float v = (c < 10) ? ((y[j] == c) ? 1.f : 0.f) : ((c == 10) ? 1.f : 0.f);
        int fid = j >> 5;
        int l   = ((j >> 3) & 3) * 16 + c;
        Vf[fid * 512 + l * 8 + (j & 7)] = f2bf(v);
    }
}

// ------------------------------- embed -------------------------------------
#define HSTR 136   // 128 + 8 pad, rows 272B (16B multiple)

__global__ __launch_bounds__(256) void k_embed(
    const float* __restrict__ X, const float* __restrict__ Xtr,
    const u16* __restrict__ W1f, const float* __restrict__ b1,
    const u16* __restrict__ W2f, const float* __restrict__ b2,
    u16* __restrict__ Etf, u16* __restrict__ Etrf)
{
    __shared__ __align__(16) u16 Hbuf[4][16][HSTR];
    const int w = threadIdx.x >> 6, lane = threadIdx.x & 63;
    const int m = lane & 15, g = lane >> 4;
    const int strip = blockIdx.x * 4 + w;        // 0..1535, 16 rows each
    const int row0  = strip * 16;
    const bool isTest = (row0 < 8192);
    const float* src = isTest ? (X + (size_t)row0 * 64)
                              : (Xtr + (size_t)(row0 - 8192) * 64);
    const floatx4 fz = {0.f, 0.f, 0.f, 0.f};

    // A-frags for this lane's row (m) of the strip
    const float* prow = src + m * 64;
    short8 a0, a1;
    {
        floatx4 x0 = *(const floatx4*)(prow + g * 8);
        floatx4 x1 = *(const floatx4*)(prow + g * 8 + 4);
        floatx4 x2 = *(const floatx4*)(prow + 32 + g * 8);
        floatx4 x3 = *(const floatx4*)(prow + 32 + g * 8 + 4);
        #pragma unroll
        for (int j = 0; j < 4; j++) { a0[j] = (short)f2bf(x0[j]); a0[4 + j] = (short)f2bf(x1[j]); }
        #pragma unroll
        for (int j = 0; j < 4; j++) { a1[j] = (short)f2bf(x2[j]); a1[4 + j] = (short)f2bf(x3[j]); }
    }

    // GEMM1: H[16x128] = relu(A @ W1 + b1) -> private LDS (bf16)
    #pragma unroll
    for (int nt = 0; nt < 8; nt++) {
        short8 bw0 = *(const short8*)(W1f + (nt * 2 + 0) * 512 + lane * 8);
        short8 bw1 = *(const short8*)(W1f + (nt * 2 + 1) * 512 + lane * 8);
        floatx4 acc = __builtin_amdgcn_mfma_f32_16x16x32_bf16(a0, bw0, fz, 0, 0, 0);
        acc = __builtin_amdgcn_mfma_f32_16x16x32_bf16(a1, bw1, acc, 0, 0, 0);
        float bias = b1[nt * 16 + m];
        #pragma unroll
        for (int r = 0; r < 4; r++) {
            float h = acc[r] + bias;
            h = h > 0.f ? h : 0.f;
            Hbuf[w][g * 4 + r][nt * 16 + m] = f2bf(h);   // C/D: row=g*4+r, col=n
        }
    }

    // GEMM2: E[16x64] = H @ W2 + b2   (A-frags from private LDS)
    short8 ha[4];
    #pragma unroll
    for (int kt = 0; kt < 4; kt++)
        ha[kt] = *(const short8*)(&Hbuf[w][m][kt * 32 + g * 8]);

    float ef[4][4];   // [nt][r]
    #pragma unroll
    for (int nt = 0; nt < 4; nt++) {
        floatx4 acc = fz;
        #pragma unroll
        for (int kt = 0; kt < 4; kt++) {
            short8 bw = *(const short8*)(W2f + (nt * 4 + kt) * 512 + lane * 8);
            acc = __builtin_amdgcn_mfma_f32_16x16x32_bf16(ha[kt], bw, acc, 0, 0, 0);
        }
        float bias = b2[nt * 16 + m];
        #pragma unroll
        for (int r = 0; r < 4; r++) ef[nt][r] = acc[r] + bias;
    }

    // Row norms: reduce squares over 64 cols (4 regs/lane + 16-lane butterfly)
    float rn[4];
    #pragma unroll
    for (int r = 0; r < 4; r++) {
        float ss = 0.f;
        #pragma unroll
        for (int nt = 0; nt < 4; nt++) ss += ef[nt][r] * ef[nt][r];
        ss += __shfl_xor(ss, 1);
        ss += __shfl_xor(ss, 2);
        ss += __shfl_xor(ss, 4);
        ss += __shfl_xor(ss, 8);
        rn[r] = rsqrtf(fmaxf(ss, 1e-30f));
    }

    // Store normalized bf16 embedding in frag-ready layout
    u16* dst = isTest ? Etf : Etrf;
    const int stile = (isTest ? row0 : row0 - 8192) >> 4;
    #pragma unroll
    for (int nt = 0; nt < 4; nt++) {
        int col = nt * 16 + m;
        int kt = col >> 5, gg = (col >> 3) & 3, jj = col & 7;
        #pragma unroll
        for (int r = 0; r < 4; r++) {
            int rloc = g * 4 + r;
            dst[(stile * 2 + kt) * 512 + (gg * 16 + rloc) * 8 + jj] =
                f2bf(ef[nt][r] * rn[r]);
        }
    }
}

// ------------------------------- main --------------------------------------
#define TS 8        // train splits (gridDim.y)
#define PSTR 40     // P rows: 32 data + 8 pad bf16, 80B (16B multiple)

__global__ __launch_bounds__(256, 4) void k_main(
    const u16* __restrict__ Etf, const u16* __restrict__ Etrf,
    const u16* __restrict__ Vf, float* __restrict__ acc)
{
    __shared__ __align__(16) u16 Pbuf[4][64][PSTR];
    __shared__ float Obuf[4][64][16];
    const int w = threadIdx.x >> 6, lane = threadIdx.x & 63;
    const int m = lane & 15, g = lane >> 4;
    const int bx = blockIdx.x, by = blockIdx.y;
    const floatx4 fz = {0.f, 0.f, 0.f, 0.f};

    // Resident A-frags: 64 test rows = 4 m-subtiles x 2 k-frags
    short8 a[4][2];
    #pragma unroll
    for (int ms = 0; ms < 4; ms++) {
        int stile = bx * 4 + ms;
        a[ms][0] = *(const short8*)(Etf + (stile * 2 + 0) * 512 + lane * 8);
        a[ms][1] = *(const short8*)(Etf + (stile * 2 + 1) * 512 + lane * 8);
    }

    floatx4 o[4] = {fz, fz, fz, fz};
    const int wstart = by * 2048 + w * 512;     // this wave's train slice

    for (int tg = 0; tg < 16; tg++) {           // 32 trains per group
        const int tb32 = wstart + tg * 32;
        short8 vfrag = *(const short8*)(Vf + (tb32 >> 5) * 512 + lane * 8);

        #pragma unroll
        for (int half = 0; half < 2; half++) {
            const int tb = tb32 + half * 16;
            const int f = tb >> 4;
            short8 b0 = *(const short8*)(Etrf + (f * 2 + 0) * 512 + lane * 8);
            short8 b1 = *(const short8*)(Etrf + (f * 2 + 1) * 512 + lane * 8);
            #pragma unroll
            for (int ms = 0; ms < 4; ms++) {
                floatx4 s = __builtin_amdgcn_mfma_f32_16x16x32_bf16(a[ms][0], b0, fz, 0, 0, 0);
                s = __builtin_amdgcn_mfma_f32_16x16x32_bf16(a[ms][1], b1, s, 0, 0, 0);
                #pragma unroll
                for (int r = 0; r < 4; r++) {
                    float p = __expf(s[r]);     // s in [-1,1]: no max needed
                    // C/D -> P[m=test][k=train_local]; per-wave private LDS
                    Pbuf[w][ms * 16 + g * 4 + r][half * 16 + m] = f2bf(p);
                }
            }
        }
        // PV: O[16x16] += P[16x32] @ V[32x16] per m-subtile
        #pragma unroll
        for (int ms = 0; ms < 4; ms++) {
            short8 pa = *(const short8*)(&Pbuf[w][ms * 16 + m][g * 8]);
            o[ms] = __builtin_amdgcn_mfma_f32_16x16x32_bf16(pa, vfrag, o[ms], 0, 0, 0);
        }
    }

    // Combine 4 waves in LDS, then one atomicAdd per (row,col)
    #pragma unroll
    for (int ms = 0; ms < 4; ms++)
        #pragma unroll
        for (int r = 0; r < 4; r++)
            Obuf[w][ms * 16 + g * 4 + r][m] = o[ms][r];
    __syncthreads();
    for (int i = threadIdx.x; i < 1024; i += 256) {
        int mm = i >> 4, c = i & 15;
        float s = Obuf[0][mm][c] + Obuf[1][mm][c] + Obuf[2][mm][c] + Obuf[3][mm][c];
        atomicAdd(&acc[(bx * 64 + mm) * 16 + c], s);
    }
}

// ------------------------------- final -------------------------------------
__global__ __launch_bounds__(256) void k_final(
    const float* __restrict__ acc, float* __restrict__ out)
{
    int row = blockIdx.x * 256 + threadIdx.x;
    if (row < 8192) {
        float inv = 1.0f / acc[row * 16 + 10];
        #pragma unroll
        for (int c = 0; c < 10; c++)
            out[row * 10 + c] = acc[row * 16 + c] * inv;
    }
}

// ------------------------------ launcher -----------------------------------
extern "C" void kernel_launch(void* const* d_in, const int* in_sizes, int n_in,
                              void* d_out, int out_size, void* d_ws, size_t ws_size,
                              hipStream_t stream)
{
    const float* X   = (const float*)d_in[0];   // [8192,64]
    const float* Xtr = (const float*)d_in[1];   // [16384,64]
    const int*   y   = (const int*)d_in[2];     // [16384]
    const float* W1  = (const float*)d_in[3];   // [64,128]
    const float* b1  = (const float*)d_in[4];   // [128]
    const float* W2  = (const float*)d_in[5];   // [128,64]
    const float* b2  = (const float*)d_in[6];   // [64]
    float* out = (float*)d_out;                 // [8192,10]

    char* ws = (char*)d_ws;
    float* acc = (float*)ws;                                    // 512 KB
    u16* Etf  = (u16*)(ws + 524288);                            // 1 MB
    u16* Etrf = (u16*)(ws + 524288 + 1048576);                  // 2 MB
    u16* W1f  = (u16*)(ws + 524288 + 1048576 + 2097152);        // 16 KB
    u16* W2f  = W1f + 8192;                                     // 16 KB
    u16* Vf   = W2f + 8192;                                     // 512 KB

    hipMemsetAsync(acc, 0, 8192 * 16 * sizeof(float), stream);
    k_prep<<<1024, 256, 0, stream>>>(W1, W2, y, W1f, W2f, Vf);
    k_embed<<<384, 256, 0, stream>>>(X, Xtr, W1f, b1, W2f, b2, Etf, Etrf);
    k_main<<<dim3(128, TS), 256, 0, stream>>>(Etf, Etrf, Vf, acc);
    k_final<<<32, 256, 0, stream>>>(acc, out);
}

// Round 2
// 102.966 us; speedup vs baseline: 1.1033x; 1.1033x over previous
//
#include <hip/hip_runtime.h>
#include <hip/hip_bf16.h>

// ---------------------------------------------------------------------------
// preds[i][c] = sum_j exp(cos(e_i, t_j)) [y_j==c]  /  sum_j exp(cos(e_i, t_j))
// where e = normalize(mlp(X)), t = normalize(mlp(x_train)).
// exp needs no max-subtraction: cosine <= 1 so exp(s) <= e.
//
// R2 changes vs R1:
//  * k_main computes S^T (A=train, B=test): C/D then holds 4 CONSECUTIVE
//    trains per lane for one test row -> P transpose becomes one v_perm_b32
//    pack per bf16 pair + one ds_write_b64 per 4 elements (was 4 VALU + 1
//    ds_write_b16 PER element). LDS wave-ops /4, cvt VALU /4.
//  * exp2 instead of expf: log2(e) folded into the TEST embeddings at store.
//  * bf16 by truncation (v_perm_b32): uniform relative bias cancels in the
//    num/den ratio; headroom is 4x.
//  * no atomics / no memset: per-by partial accumulators, k_final sums 8.
//
// Frag-ready layout for a bf16 matrix M[row][k] (16-row tiles, K=64):
//   elem(row,k) at tile(row>>4), kt(k>>5): ((row>>4)*2+kt)*512
//                + ( ((k>>3)&3)*16 + (row&15) )*8 + (k&7)
//   one frag = *(short8*)(base + (tile*2+kt)*512 + lane*8): a single dwordx4.
//   The SAME layout serves MFMA A-operands (row=M) and B-operands (row=N).
// ---------------------------------------------------------------------------

typedef __attribute__((ext_vector_type(8))) short short8;    // 8 bf16 = 4 VGPR
typedef __attribute__((ext_vector_type(4))) float floatx4;
typedef unsigned short u16;
typedef unsigned int u32;

#define LOG2E 1.4426950408889634f

__device__ __forceinline__ u16 f2bf(float f) {  // RNE float->bf16
    unsigned u = __float_as_uint(f);
    u += 0x7fffu + ((u >> 16) & 1u);
    return (u16)(u >> 16);
}

// ------------------------------- prep --------------------------------------
__global__ __launch_bounds__(256) void k_prep(
    const float* __restrict__ W1, const float* __restrict__ W2,
    const int* __restrict__ y, u16* __restrict__ W1f,
    u16* __restrict__ W2f, u16* __restrict__ Vf)
{
    int tid = blockIdx.x * 256 + threadIdx.x;
    if (tid < 8192) {
        // W1 [64][128] -> B-frags: fid = (n>>4)*2 + (k>>5)
        int k = tid >> 7, n = tid & 127;
        int fid = (n >> 4) * 2 + (k >> 5);
        int l   = ((k >> 3) & 3) * 16 + (n & 15);
        W1f[fid * 512 + l * 8 + (k & 7)] = f2bf(W1[k * 128 + n]);
        // W2 [128][64] -> B-frags: fid = (n>>4)*4 + (k>>5)
        int k2 = tid >> 6, n2 = tid & 63;
        int fid2 = (n2 >> 4) * 4 + (k2 >> 5);
        int l2   = ((k2 >> 3) & 3) * 16 + (n2 & 15);
        W2f[fid2 * 512 + l2 * 8 + (k2 & 7)] = f2bf(W2[k2 * 64 + n2]);
    }
    if (tid < 262144) {
        // V [16384][16]: onehot + ones col 10. B-frag over k=train, n=class.
        int j = tid >> 4, c = tid & 15;
        float v = (c < 10) ? ((y[j] == c) ? 1.f : 0.f) : ((c == 10) ? 1.f : 0.f);
        int fid = j >> 5;
        int l   = ((j >> 3) & 3) * 16 + c;
        Vf[fid * 512 + l * 8 + (j & 7)] = f2bf(v);
    }
}

// ------------------------------- embed -------------------------------------
#define HSTR 136   // 128 + 8 pad, rows 272B (16B multiple)

__global__ __launch_bounds__(256) void k_embed(
    const float* __restrict__ X, const float* __restrict__ Xtr,
    const u16* __restrict__ W1f, const float* __restrict__ b1,
    const u16* __restrict__ W2f, const float* __restrict__ b2,
    u16* __restrict__ Etf, u16* __restrict__ Etrf)
{
    __shared__ __align__(16) u16 Hbuf[4][16][HSTR];
    const int w = threadIdx.x >> 6, lane = threadIdx.x & 63;
    const int m = lane & 15, g = lane >> 4;
    const int strip = blockIdx.x * 4 + w;        // 0..1535, 16 rows each
    const int row0  = strip * 16;
    const bool isTest = (row0 < 8192);
    const float* src = isTest ? (X + (size_t)row0 * 64)
                              : (Xtr + (size_t)(row0 - 8192) * 64);
    const floatx4 fz = {0.f, 0.f, 0.f, 0.f};

    // A-frags for this lane's row (m) of the strip
    const float* prow = src + m * 64;
    short8 a0, a1;
    {
        floatx4 x0 = *(const floatx4*)(prow + g * 8);
        floatx4 x1 = *(const floatx4*)(prow + g * 8 + 4);
        floatx4 x2 = *(const floatx4*)(prow + 32 + g * 8);
        floatx4 x3 = *(const floatx4*)(prow + 32 + g * 8 + 4);
        #pragma unroll
        for (int j = 0; j < 4; j++) { a0[j] = (short)f2bf(x0[j]); a0[4 + j] = (short)f2bf(x1[j]); }
        #pragma unroll
        for (int j = 0; j < 4; j++) { a1[j] = (short)f2bf(x2[j]); a1[4 + j] = (short)f2bf(x3[j]); }
    }

    // GEMM1: H[16x128] = relu(A @ W1 + b1) -> private LDS (bf16)
    #pragma unroll
    for (int nt = 0; nt < 8; nt++) {
        short8 bw0 = *(const short8*)(W1f + (nt * 2 + 0) * 512 + lane * 8);
        short8 bw1 = *(const short8*)(W1f + (nt * 2 + 1) * 512 + lane * 8);
        floatx4 acc = __builtin_amdgcn_mfma_f32_16x16x32_bf16(a0, bw0, fz, 0, 0, 0);
        acc = __builtin_amdgcn_mfma_f32_16x16x32_bf16(a1, bw1, acc, 0, 0, 0);
        float bias = b1[nt * 16 + m];
        #pragma unroll
        for (int r = 0; r < 4; r++) {
            float h = acc[r] + bias;
            h = h > 0.f ? h : 0.f;
            Hbuf[w][g * 4 + r][nt * 16 + m] = f2bf(h);   // C/D: row=g*4+r, col=n
        }
    }

    // GEMM2: E[16x64] = H @ W2 + b2   (A-frags from private LDS)
    short8 ha[4];
    #pragma unroll
    for (int kt = 0; kt < 4; kt++)
        ha[kt] = *(const short8*)(&Hbuf[w][m][kt * 32 + g * 8]);

    float ef[4][4];   // [nt][r]
    #pragma unroll
    for (int nt = 0; nt < 4; nt++) {
        floatx4 acc = fz;
        #pragma unroll
        for (int kt = 0; kt < 4; kt++) {
            short8 bw = *(const short8*)(W2f + (nt * 4 + kt) * 512 + lane * 8);
            acc = __builtin_amdgcn_mfma_f32_16x16x32_bf16(ha[kt], bw, acc, 0, 0, 0);
        }
        float bias = b2[nt * 16 + m];
        #pragma unroll
        for (int r = 0; r < 4; r++) ef[nt][r] = acc[r] + bias;
    }

    // Row norms: reduce squares over 64 cols (4 regs/lane + 16-lane butterfly)
    // Test side gets log2(e) folded in so k_main can use exp2 directly.
    const float sc = isTest ? LOG2E : 1.0f;
    float rn[4];
    #pragma unroll
    for (int r = 0; r < 4; r++) {
        float ss = 0.f;
        #pragma unroll
        for (int nt = 0; nt < 4; nt++) ss += ef[nt][r] * ef[nt][r];
        ss += __shfl_xor(ss, 1);
        ss += __shfl_xor(ss, 2);
        ss += __shfl_xor(ss, 4);
        ss += __shfl_xor(ss, 8);
        rn[r] = rsqrtf(fmaxf(ss, 1e-30f)) * sc;
    }

    // Store normalized bf16 embedding in frag-ready layout
    u16* dst = isTest ? Etf : Etrf;
    const int stile = (isTest ? row0 : row0 - 8192) >> 4;
    #pragma unroll
    for (int nt = 0; nt < 4; nt++) {
        int col = nt * 16 + m;
        int kt = col >> 5, gg = (col >> 3) & 3, jj = col & 7;
        #pragma unroll
        for (int r = 0; r < 4; r++) {
            int rloc = g * 4 + r;
            dst[(stile * 2 + kt) * 512 + (gg * 16 + rloc) * 8 + jj] =
                f2bf(ef[nt][r] * rn[r]);
        }
    }
}

// ------------------------------- main --------------------------------------
#define TS 8        // train splits (gridDim.y)
#define PSTR 40     // P row stride in u16: 80 B = 16B multiple (b128-clean)

__global__ __launch_bounds__(256, 4) void k_main(
    const u16* __restrict__ Etf, const u16* __restrict__ Etrf,
    const u16* __restrict__ Vf, float* __restrict__ accp)
{
    __shared__ __align__(16) u16 Pbuf[4][64][PSTR];   // [wave][test][train_loc]
    __shared__ float Obuf[4][64][16];
    const int w = threadIdx.x >> 6, lane = threadIdx.x & 63;
    const int m = lane & 15, g = lane >> 4;
    const int bx = blockIdx.x, by = blockIdx.y;
    const floatx4 fz = {0.f, 0.f, 0.f, 0.f};

    // Resident TEST fragments, used as MFMA B-operand (n = test col = m)
    short8 b[4][2];
    #pragma unroll
    for (int ns = 0; ns < 4; ns++) {
        int stile = bx * 4 + ns;
        b[ns][0] = *(const short8*)(Etf + (stile * 2 + 0) * 512 + lane * 8);
        b[ns][1] = *(const short8*)(Etf + (stile * 2 + 1) * 512 + lane * 8);
    }

    floatx4 o[4] = {fz, fz, fz, fz};
    const int wstart = by * 2048 + w * 512;     // this wave's train slice

    for (int tg = 0; tg < 16; tg++) {           // 32 trains per group
        const int tb32 = wstart + tg * 32;
        short8 vfrag = *(const short8*)(Vf + (tb32 >> 5) * 512 + lane * 8);

        #pragma unroll
        for (int half = 0; half < 2; half++) {
            const int f = (tb32 >> 4) + half;   // 16-train tile
            short8 a0 = *(const short8*)(Etrf + (f * 2 + 0) * 512 + lane * 8);
            short8 a1 = *(const short8*)(Etrf + (f * 2 + 1) * 512 + lane * 8);
            #pragma unroll
            for (int ns = 0; ns < 4; ns++) {
                // S^T: row = train (g*4+r), col = test (m within subtile ns)
                floatx4 s = __builtin_amdgcn_mfma_f32_16x16x32_bf16(a0, b[ns][0], fz, 0, 0, 0);
                s = __builtin_amdgcn_mfma_f32_16x16x32_bf16(a1, b[ns][1], s, 0, 0, 0);
                // p = 2^s (log2e pre-folded); pack 4 consecutive trains as
                // bf16-by-truncation via v_perm_b32, one ds_write_b64.
                u32 p0 = __float_as_uint(__builtin_amdgcn_exp2f(s[0]));
                u32 p1 = __float_as_uint(__builtin_amdgcn_exp2f(s[1]));
                u32 p2 = __float_as_uint(__builtin_amdgcn_exp2f(s[2]));
                u32 p3 = __float_as_uint(__builtin_amdgcn_exp2f(s[3]));
                u32 pk0 = __builtin_amdgcn_perm(p1, p0, 0x07060302u); // hi16s
                u32 pk1 = __builtin_amdgcn_perm(p3, p2, 0x07060302u);
                u32* dst = (u32*)&Pbuf[w][ns * 16 + m][half * 16 + g * 4];
                dst[0] = pk0; dst[1] = pk1;     // 8B store, 8B-aligned
            }
        }
        // PV: O[16x16] += P[16x32] @ V[32x16] per test subtile
        #pragma unroll
        for (int ms = 0; ms < 4; ms++) {
            short8 pa = *(const short8*)(&Pbuf[w][ms * 16 + m][g * 8]);
            o[ms] = __builtin_amdgcn_mfma_f32_16x16x32_bf16(pa, vfrag, o[ms], 0, 0, 0);
        }
    }

    // Combine 4 waves in LDS, then plain store to this by's partial buffer
    #pragma unroll
    for (int ms = 0; ms < 4; ms++)
        #pragma unroll
        for (int r = 0; r < 4; r++)
            Obuf[w][ms * 16 + g * 4 + r][m] = o[ms][r];
    __syncthreads();
    for (int i = threadIdx.x; i < 1024; i += 256) {
        int mm = i >> 4, c = i & 15;
        float s = Obuf[0][mm][c] + Obuf[1][mm][c] + Obuf[2][mm][c] + Obuf[3][mm][c];
        accp[((size_t)by * 8192 + bx * 64 + mm) * 16 + c] = s;
    }
}

// ------------------------------- final -------------------------------------
__global__ __launch_bounds__(256) void k_final(
    const float* __restrict__ accp, float* __restrict__ out)
{
    int row = blockIdx.x * 256 + threadIdx.x;
    if (row < 8192) {
        floatx4 s0 = {0.f,0.f,0.f,0.f}, s1 = s0, s2 = s0;
        #pragma unroll
        for (int p = 0; p < TS; p++) {
            const floatx4* src = (const floatx4*)(accp + ((size_t)p * 8192 + row) * 16);
            s0 += src[0]; s1 += src[1]; s2 += src[2];
        }
        float inv = 1.0f / s2[2];               // col 10 = denominator
        out[row * 10 + 0] = s0[0] * inv;
        out[row * 10 + 1] = s0[1] * inv;
        out[row * 10 + 2] = s0[2] * inv;
        out[row * 10 + 3] = s0[3] * inv;
        out[row * 10 + 4] = s1[0] * inv;
        out[row * 10 + 5] = s1[1] * inv;
        out[row * 10 + 6] = s1[2] * inv;
        out[row * 10 + 7] = s1[3] * inv;
        out[row * 10 + 8] = s2[0] * inv;
        out[row * 10 + 9] = s2[1] * inv;
    }
}

// ------------------------------ launcher -----------------------------------
extern "C" void kernel_launch(void* const* d_in, const int* in_sizes, int n_in,
                              void* d_out, int out_size, void* d_ws, size_t ws_size,
                              hipStream_t stream)
{
    const float* X   = (const float*)d_in[0];   // [8192,64]
    const float* Xtr = (const float*)d_in[1];   // [16384,64]
    const int*   y   = (const int*)d_in[2];     // [16384]
    const float* W1  = (const float*)d_in[3];   // [64,128]
    const float* b1  = (const float*)d_in[4];   // [128]
    const float* W2  = (const float*)d_in[5];   // [128,64]
    const float* b2  = (const float*)d_in[6];   // [64]
    float* out = (float*)d_out;                 // [8192,10]

    char* ws = (char*)d_ws;
    float* accp = (float*)ws;                                   // 4 MB (8 partials)
    u16* Etf  = (u16*)(ws + 4194304);                           // 1 MB
    u16* Etrf = (u16*)(ws + 4194304 + 1048576);                 // 2 MB
    u16* W1f  = (u16*)(ws + 4194304 + 1048576 + 2097152);       // 16 KB
    u16* W2f  = W1f + 8192;                                     // 16 KB
    u16* Vf   = W2f + 8192;                                     // 512 KB

    k_prep<<<1024, 256, 0, stream>>>(W1, W2, y, W1f, W2f, Vf);
    k_embed<<<384, 256, 0, stream>>>(X, Xtr, W1f, b1, W2f, b2, Etf, Etrf);
    k_main<<<dim3(128, TS), 256, 0, stream>>>(Etf, Etrf, Vf, accp);
    k_final<<<32, 256, 0, stream>>>(accp, out);
}

// Round 3
// 98.155 us; speedup vs baseline: 1.1574x; 1.0490x over previous
//
#include <hip/hip_runtime.h>
#include <hip/hip_bf16.h>

// ---------------------------------------------------------------------------
// preds[i][c] = sum_j exp(cos(e_i, t_j)) [y_j==c]  /  sum_j exp(cos(e_i, t_j))
// where e = normalize(mlp(X)), t = normalize(mlp(x_train)).
// exp needs no max-subtraction: cosine <= 1 so exp(s) <= e.
//
// R3 changes vs R2:
//  * NO P LDS round-trip: S^T C/D regs feed the PV MFMA directly. The PV
//    V-operand is stored k-PERMUTED (tau(quad,j) = (j>>2)*16 + quad*4 + (j&3))
//    so that pa = {bf16(s_tile0[0..3]), bf16(s_tile1[0..3])} is a valid
//    16x16x32 A-fragment. Sum over permuted k == sum over trains (bijection).
//  * TM=128 test rows/block (8 subtiles): halves Etrf L2 traffic (256->128MB).
//  * Explicit register prefetch of next 32-train group (2 blocks/CU).
//  * k_prep merged into k_embed: W1/W2 frags built per-block in LDS; grid
//    blocks 384..447 generate the permuted V-frags. One fewer launch.
//
// Frag-ready layout for a bf16 matrix M[row][k] (16-row tiles, K=64):
//   elem(row,k) at ((row>>4)*2 + (k>>5))*512 + (((k>>3)&3)*16 + (row&15))*8
//                + (k&7)
//   one frag = *(short8*)(base + fid*512 + lane*8): a single dwordx4.
//   The SAME layout serves MFMA A-operands (row=M) and B-operands (row=N).
// ---------------------------------------------------------------------------

typedef __attribute__((ext_vector_type(8))) short short8;    // 8 bf16 = 4 VGPR
typedef __attribute__((ext_vector_type(4))) float floatx4;
typedef unsigned short u16;
typedef unsigned int u32;

#define LOG2E 1.4426950408889634f
#define TS 8          // train splits (gridDim.y)

__device__ __forceinline__ u16 f2bf(float f) {  // RNE float->bf16
    unsigned u = __float_as_uint(f);
    u += 0x7fffu + ((u >> 16) & 1u);
    return (u16)(u >> 16);
}

// ------------------------------- embed (+prep) -----------------------------
#define HSTR 136   // 128 + 8 pad u16, rows 272B (16B multiple)

__global__ __launch_bounds__(256) void k_embed(
    const float* __restrict__ X, const float* __restrict__ Xtr,
    const float* __restrict__ W1, const float* __restrict__ b1,
    const float* __restrict__ W2, const float* __restrict__ b2,
    const int* __restrict__ y,
    u16* __restrict__ Etf, u16* __restrict__ Etrf, u16* __restrict__ Vf)
{
    const int bx = blockIdx.x;

    if (bx >= 384) {
        // ---- V-frag generation, k-permuted for direct-feed PV ----
        // elem addr e: f32=e>>9, l=(e>>3)&63, j=e&7; quad=l>>4, n=l&15,
        // t=j>>2, r=j&3; train = f32*32 + t*16 + quad*4 + r.
        const int t0 = ((bx - 384) * 256 + threadIdx.x) * 32;
        #pragma unroll
        for (int i8 = 0; i8 < 4; i8++) {
            short8 vv;
            #pragma unroll
            for (int j = 0; j < 8; j++) {
                int e = t0 + i8 * 8 + j;
                int f32 = e >> 9, l = (e >> 3) & 63, jj = e & 7;
                int quad = l >> 4, n = l & 15, tt = jj >> 2, r = jj & 3;
                int train = f32 * 32 + tt * 16 + quad * 4 + r;
                int yv = y[train];
                vv[j] = (n == yv || n == 10) ? (short)0x3F80 : (short)0;
            }
            *(short8*)&Vf[t0 + i8 * 8] = vv;
        }
        return;
    }

    __shared__ __align__(16) u16 W1L[8192];     // 16 KB, frag layout
    __shared__ __align__(16) u16 W2L[8192];     // 16 KB, frag layout
    __shared__ __align__(16) u16 Hbuf[4][16][HSTR];

    // ---- cooperative W1/W2 -> bf16 frag conversion into LDS ----
    {
        const int t = threadIdx.x;
        #pragma unroll
        for (int i8 = 0; i8 < 4; i8++) {
            short8 v1, v2;
            #pragma unroll
            for (int j = 0; j < 8; j++) {
                int e = t * 32 + i8 * 8 + j;
                int fid = e >> 9, l = (e >> 3) & 63, jj = e & 7;
                int n1 = (fid >> 1) * 16 + (l & 15);
                int k1 = (fid & 1) * 32 + (l >> 4) * 8 + jj;
                v1[j] = (short)f2bf(W1[k1 * 128 + n1]);
                int n2 = (fid >> 2) * 16 + (l & 15);
                int k2 = (fid & 3) * 32 + (l >> 4) * 8 + jj;
                v2[j] = (short)f2bf(W2[k2 * 64 + n2]);
            }
            *(short8*)&W1L[t * 32 + i8 * 8] = v1;
            *(short8*)&W2L[t * 32 + i8 * 8] = v2;
        }
    }
    __syncthreads();

    const int w = threadIdx.x >> 6, lane = threadIdx.x & 63;
    const int m = lane & 15, g = lane >> 4;
    const int strip = bx * 4 + w;                // 0..1535, 16 rows each
    const int row0  = strip * 16;
    const bool isTest = (row0 < 8192);
    const float* src = isTest ? (X + (size_t)row0 * 64)
                              : (Xtr + (size_t)(row0 - 8192) * 64);
    const floatx4 fz = {0.f, 0.f, 0.f, 0.f};

    // A-frags for this lane's row (m) of the strip
    const float* prow = src + m * 64;
    short8 a0, a1;
    {
        floatx4 x0 = *(const floatx4*)(prow + g * 8);
        floatx4 x1 = *(const floatx4*)(prow + g * 8 + 4);
        floatx4 x2 = *(const floatx4*)(prow + 32 + g * 8);
        floatx4 x3 = *(const floatx4*)(prow + 32 + g * 8 + 4);
        #pragma unroll
        for (int j = 0; j < 4; j++) { a0[j] = (short)f2bf(x0[j]); a0[4 + j] = (short)f2bf(x1[j]); }
        #pragma unroll
        for (int j = 0; j < 4; j++) { a1[j] = (short)f2bf(x2[j]); a1[4 + j] = (short)f2bf(x3[j]); }
    }

    // GEMM1: H[16x128] = relu(A @ W1 + b1) -> private LDS (bf16)
    #pragma unroll
    for (int nt = 0; nt < 8; nt++) {
        short8 bw0 = *(const short8*)&W1L[(nt * 2 + 0) * 512 + lane * 8];
        short8 bw1 = *(const short8*)&W1L[(nt * 2 + 1) * 512 + lane * 8];
        floatx4 acc = __builtin_amdgcn_mfma_f32_16x16x32_bf16(a0, bw0, fz, 0, 0, 0);
        acc = __builtin_amdgcn_mfma_f32_16x16x32_bf16(a1, bw1, acc, 0, 0, 0);
        float bias = b1[nt * 16 + m];
        #pragma unroll
        for (int r = 0; r < 4; r++) {
            float h = acc[r] + bias;
            h = h > 0.f ? h : 0.f;
            Hbuf[w][g * 4 + r][nt * 16 + m] = f2bf(h);   // C/D: row=g*4+r, col=n
        }
    }

    // GEMM2: E[16x64] = H @ W2 + b2   (A-frags from private LDS)
    short8 ha[4];
    #pragma unroll
    for (int kt = 0; kt < 4; kt++)
        ha[kt] = *(const short8*)(&Hbuf[w][m][kt * 32 + g * 8]);

    float ef[4][4];   // [nt][r]
    #pragma unroll
    for (int nt = 0; nt < 4; nt++) {
        floatx4 acc = fz;
        #pragma unroll
        for (int kt = 0; kt < 4; kt++) {
            short8 bw = *(const short8*)&W2L[(nt * 4 + kt) * 512 + lane * 8];
            acc = __builtin_amdgcn_mfma_f32_16x16x32_bf16(ha[kt], bw, acc, 0, 0, 0);
        }
        float bias = b2[nt * 16 + m];
        #pragma unroll
        for (int r = 0; r < 4; r++) ef[nt][r] = acc[r] + bias;
    }

    // Row norms (4 regs/lane + 16-lane butterfly); log2(e) folded into test.
    const float sc = isTest ? LOG2E : 1.0f;
    float rn[4];
    #pragma unroll
    for (int r = 0; r < 4; r++) {
        float ss = 0.f;
        #pragma unroll
        for (int nt = 0; nt < 4; nt++) ss += ef[nt][r] * ef[nt][r];
        ss += __shfl_xor(ss, 1);
        ss += __shfl_xor(ss, 2);
        ss += __shfl_xor(ss, 4);
        ss += __shfl_xor(ss, 8);
        rn[r] = rsqrtf(fmaxf(ss, 1e-30f)) * sc;
    }

    // Store normalized bf16 embedding in frag-ready layout
    u16* dst = isTest ? Etf : Etrf;
    const int stile = (isTest ? row0 : row0 - 8192) >> 4;
    #pragma unroll
    for (int nt = 0; nt < 4; nt++) {
        int col = nt * 16 + m;
        int kt = col >> 5, gg = (col >> 3) & 3, jj = col & 7;
        #pragma unroll
        for (int r = 0; r < 4; r++) {
            int rloc = g * 4 + r;
            dst[(stile * 2 + kt) * 512 + (gg * 16 + rloc) * 8 + jj] =
                f2bf(ef[nt][r] * rn[r]);
        }
    }
}

// ------------------------------- main --------------------------------------
__global__ __launch_bounds__(256, 2) void k_main(
    const u16* __restrict__ Etf, const u16* __restrict__ Etrf,
    const u16* __restrict__ Vf, float* __restrict__ accp)
{
    __shared__ float Obuf[4][128][16];          // 32 KB
    const int w = threadIdx.x >> 6, lane = threadIdx.x & 63;
    const int m = lane & 15, g = lane >> 4;
    const int bx = blockIdx.x, by = blockIdx.y;
    const floatx4 fz = {0.f, 0.f, 0.f, 0.f};

    // Resident TEST fragments (B-operand of the S^T MFMA): 8 subtiles x 2
    short8 b[8][2];
    #pragma unroll
    for (int ns = 0; ns < 8; ns++) {
        int stile = bx * 8 + ns;
        b[ns][0] = *(const short8*)(Etf + (stile * 2 + 0) * 512 + lane * 8);
        b[ns][1] = *(const short8*)(Etf + (stile * 2 + 1) * 512 + lane * 8);
    }

    floatx4 o[8] = {fz, fz, fz, fz, fz, fz, fz, fz};
    const int wstart = by * 2048 + w * 512;     // this wave's train slice
    const int fbase = wstart >> 4;              // 16-train tile base
    const int vbase = wstart >> 5;              // 32-train vfrag base

    // Prefetch group 0: 4 train frags (2 tiles x 2 k) + permuted V-frag
    short8 a0 = *(const short8*)(Etrf + (fbase + 0) * 512 + lane * 8);
    short8 a1 = *(const short8*)(Etrf + (fbase + 1) * 512 + lane * 8);
    short8 a2 = *(const short8*)(Etrf + (fbase + 2) * 512 + lane * 8);
    short8 a3 = *(const short8*)(Etrf + (fbase + 3) * 512 + lane * 8);
    short8 vf = *(const short8*)(Vf + (vbase + 0) * 512 + lane * 8);

    for (int g32 = 0; g32 < 16; g32++) {        // 32 trains per group
        // prefetch next group (clamped; extra regs, hides L2 latency)
        const int gn = (g32 < 15) ? g32 + 1 : 15;
        short8 na0 = *(const short8*)(Etrf + (fbase + gn * 2 + 0) * 512 + lane * 8);
        short8 na1 = *(const short8*)(Etrf + (fbase + gn * 2 + 1) * 512 + lane * 8);
        short8 na2 = *(const short8*)(Etrf + (fbase + gn * 2 + 2) * 512 + lane * 8);
        short8 na3 = *(const short8*)(Etrf + (fbase + gn * 2 + 3) * 512 + lane * 8);
        short8 nvf = *(const short8*)(Vf + (vbase + gn) * 512 + lane * 8);

        #pragma unroll
        for (int ns = 0; ns < 8; ns++) {
            // S^T for two 16-train tiles: row=train (quad*4+r), col=test (m)
            floatx4 s0 = __builtin_amdgcn_mfma_f32_16x16x32_bf16(a0, b[ns][0], fz, 0, 0, 0);
            s0 = __builtin_amdgcn_mfma_f32_16x16x32_bf16(a1, b[ns][1], s0, 0, 0, 0);
            floatx4 s1 = __builtin_amdgcn_mfma_f32_16x16x32_bf16(a2, b[ns][0], fz, 0, 0, 0);
            s1 = __builtin_amdgcn_mfma_f32_16x16x32_bf16(a3, b[ns][1], s1, 0, 0, 0);
            // p = 2^s (log2e folded into test embd); bf16-truncate pack.
            u32 p0 = __float_as_uint(__builtin_amdgcn_exp2f(s0[0]));
            u32 p1 = __float_as_uint(__builtin_amdgcn_exp2f(s0[1]));
            u32 p2 = __float_as_uint(__builtin_amdgcn_exp2f(s0[2]));
            u32 p3 = __float_as_uint(__builtin_amdgcn_exp2f(s0[3]));
            u32 p4 = __float_as_uint(__builtin_amdgcn_exp2f(s1[0]));
            u32 p5 = __float_as_uint(__builtin_amdgcn_exp2f(s1[1]));
            u32 p6 = __float_as_uint(__builtin_amdgcn_exp2f(s1[2]));
            u32 p7 = __float_as_uint(__builtin_amdgcn_exp2f(s1[3]));
            u32 pk[4];
            pk[0] = __builtin_amdgcn_perm(p1, p0, 0x07060302u);
            pk[1] = __builtin_amdgcn_perm(p3, p2, 0x07060302u);
            pk[2] = __builtin_amdgcn_perm(p5, p4, 0x07060302u);
            pk[3] = __builtin_amdgcn_perm(p7, p6, 0x07060302u);
            short8 pa = *(short8*)pk;   // A-frag: k-permuted, matches Vf perm
            o[ns] = __builtin_amdgcn_mfma_f32_16x16x32_bf16(pa, vf, o[ns], 0, 0, 0);
        }
        a0 = na0; a1 = na1; a2 = na2; a3 = na3; vf = nvf;
    }

    // Combine 4 waves in LDS, then plain store to this by's partial buffer
    #pragma unroll
    for (int ms = 0; ms < 8; ms++)
        #pragma unroll
        for (int r = 0; r < 4; r++)
            Obuf[w][ms * 16 + g * 4 + r][m] = o[ms][r];
    __syncthreads();
    for (int i = threadIdx.x; i < 2048; i += 256) {
        int mm = i >> 4, c = i & 15;
        float s = Obuf[0][mm][c] + Obuf[1][mm][c] + Obuf[2][mm][c] + Obuf[3][mm][c];
        accp[((size_t)by * 8192 + bx * 128 + mm) * 16 + c] = s;
    }
}

// ------------------------------- final -------------------------------------
__global__ __launch_bounds__(256) void k_final(
    const float* __restrict__ accp, float* __restrict__ out)
{
    int row = blockIdx.x * 256 + threadIdx.x;
    if (row < 8192) {
        floatx4 s0 = {0.f,0.f,0.f,0.f}, s1 = s0, s2 = s0;
        #pragma unroll
        for (int p = 0; p < TS; p++) {
            const floatx4* src = (const floatx4*)(accp + ((size_t)p * 8192 + row) * 16);
            s0 += src[0]; s1 += src[1]; s2 += src[2];
        }
        float inv = 1.0f / s2[2];               // col 10 = denominator
        out[row * 10 + 0] = s0[0] * inv;
        out[row * 10 + 1] = s0[1] * inv;
        out[row * 10 + 2] = s0[2] * inv;
        out[row * 10 + 3] = s0[3] * inv;
        out[row * 10 + 4] = s1[0] * inv;
        out[row * 10 + 5] = s1[1] * inv;
        out[row * 10 + 6] = s1[2] * inv;
        out[row * 10 + 7] = s1[3] * inv;
        out[row * 10 + 8] = s2[0] * inv;
        out[row * 10 + 9] = s2[1] * inv;
    }
}

// ------------------------------ launcher -----------------------------------
extern "C" void kernel_launch(void* const* d_in, const int* in_sizes, int n_in,
                              void* d_out, int out_size, void* d_ws, size_t ws_size,
                              hipStream_t stream)
{
    const float* X   = (const float*)d_in[0];   // [8192,64]
    const float* Xtr = (const float*)d_in[1];   // [16384,64]
    const int*   y   = (const int*)d_in[2];     // [16384]
    const float* W1  = (const float*)d_in[3];   // [64,128]
    const float* b1  = (const float*)d_in[4];   // [128]
    const float* W2  = (const float*)d_in[5];   // [128,64]
    const float* b2  = (const float*)d_in[6];   // [64]
    float* out = (float*)d_out;                 // [8192,10]

    char* ws = (char*)d_ws;
    float* accp = (float*)ws;                                   // 4 MB
    u16* Etf  = (u16*)(ws + 4194304);                           // 1 MB
    u16* Etrf = (u16*)(ws + 4194304 + 1048576);                 // 2 MB
    u16* Vf   = (u16*)(ws + 4194304 + 1048576 + 2097152);       // 1 MB (permuted V)

    k_embed<<<448, 256, 0, stream>>>(X, Xtr, W1, b1, W2, b2, y, Etf, Etrf, Vf);
    k_main<<<dim3(64, TS), 256, 0, stream>>>(Etf, Etrf, Vf, accp);
    k_final<<<32, 256, 0, stream>>>(accp, out);
}